// Round 4
// baseline (93.006 us; speedup 1.0000x reference)
//
#include <hip/hip_runtime.h>
#include <math.h>

#define G 8                  // grid cells per dim
#define NCELL (G*G*G)        // 512
#define INV_CS 0.8f          // G / 10.0
#define CS 1.25f             // 10.0 / G
#define KNN 3
#define BIGF 3.402823466e+38f

#define HIST_BLOCK 256
#define SCAN_BLOCK 512       // == NCELL
#define SEARCH_BLOCK 256
#define SPLIT 8                                   // lanes cooperating per point
#define PTS_PER_SBLOCK (SEARCH_BLOCK / SPLIT)     // 32

__device__ __forceinline__ int cell_of(float x, float y, float z) {
    int cx = (int)(x * INV_CS); cx = cx < 0 ? 0 : (cx > G-1 ? G-1 : cx);
    int cy = (int)(y * INV_CS); cy = cy < 0 ? 0 : (cy > G-1 ? G-1 : cy);
    int cz = (int)(z * INV_CS); cz = cz < 0 ? 0 : (cz > G-1 ? G-1 : cz);
    return (cx << 6) | (cy << 3) | cz;
}

__device__ __forceinline__ void pk_insert(double pk, double& m0, double& m1, double& m2) {
    const double lo0 = fmin(m0, pk);
    const double hi0 = fmax(m0, pk);
    m0 = lo0;
    const double lo1 = fmin(m1, hi0);
    const double hi1 = fmax(m1, hi0);
    m1 = lo1;
    m2 = fmin(m2, hi1);
}

// ---- K1: per-point cell id + per-segment histogram (global atomics) --------
__global__ __launch_bounds__(HIST_BLOCK) void hist_kernel(
    const float* __restrict__ coord,
    int* __restrict__ pcell,            // [N]
    int* __restrict__ hist,             // [nseg*NCELL], pre-zeroed
    int N)
{
    const int p = blockIdx.x * HIST_BLOCK + threadIdx.x;
    if (p >= N) return;
    const int s = p >> 12;              // seg == 4096
    const float x = coord[p*3 + 0];
    const float y = coord[p*3 + 1];
    const float z = coord[p*3 + 2];
    const int c = cell_of(x, y, z);
    pcell[p] = c;
    atomicAdd(&hist[(s << 9) + c], 1);
}

// ---- K2: per-segment exclusive scan (one block per segment) ----------------
__global__ __launch_bounds__(SCAN_BLOCK) void scan_kernel(
    const int* __restrict__ hist,
    int* __restrict__ cellstart,        // [nseg*(NCELL+1)]
    int* __restrict__ cursor)           // [nseg*NCELL]
{
    __shared__ int sb[NCELL];
    const int tid = threadIdx.x;
    const int s   = blockIdx.x;
    const int own = hist[(s << 9) + tid];
    sb[tid] = own;
    __syncthreads();
    for (int off = 1; off < NCELL; off <<= 1) {
        const int add = (tid >= off) ? sb[tid - off] : 0;
        __syncthreads();
        sb[tid] += add;
        __syncthreads();
    }
    const int excl = sb[tid] - own;
    cellstart[s * (NCELL + 1) + tid] = excl;
    cursor[(s << 9) + tid] = excl;
    if (tid == NCELL - 1) cellstart[s * (NCELL + 1) + NCELL] = sb[tid];
}

// ---- K3: parallel scatter into cell-sorted order ---------------------------
__global__ __launch_bounds__(HIST_BLOCK) void scatter_kernel(
    const float* __restrict__ coord,
    const int* __restrict__ pcell,
    int* __restrict__ cursor,
    float4* __restrict__ sorted,        // [N]
    int N, int seg)
{
    const int p = blockIdx.x * HIST_BLOCK + threadIdx.x;
    if (p >= N) return;
    const int s = p >> 12;
    const int c = pcell[p];
    const float x = coord[p*3 + 0];
    const float y = coord[p*3 + 1];
    const float z = coord[p*3 + 2];
    const int slot = atomicAdd(&cursor[(s << 9) + c], 1);
    sorted[(long)s * seg + slot] =
        make_float4(x, y, z, __int_as_float(p & (seg - 1)));   // local orig idx
}

// ---- K4: 8 lanes/point exact 3-NN via grid + loss --------------------------
__global__ __launch_bounds__(SEARCH_BLOCK) void knn_loss(
    const float4* __restrict__ sorted,
    const int* __restrict__ cellstart,
    const float* __restrict__ pred,
    const float* __restrict__ target,
    float* __restrict__ out,
    int seg, float inv_total)
{
    __shared__ int csl[NCELL + 1];
    __shared__ float wred[SEARCH_BLOCK / 64];

    const int tid = threadIdx.x;
    const int sub = tid & (SPLIT - 1);
    const int pt  = blockIdx.x * PTS_PER_SBLOCK + (tid >> 3);  // sorted-order point
    const int s   = pt >> 12;      // seg == 4096; blocks never straddle segments
    const int j   = pt & 4095;     // slot within segment
    const long segbase = (long)s * seg;

    for (int i = tid; i < NCELL + 1; i += SEARCH_BLOCK)
        csl[i] = cellstart[s * (NCELL + 1) + i];
    __syncthreads();

    const float4 me = sorted[segbase + j];
    const int myorig = __float_as_int(me.w);
    const int cx = (me.x * INV_CS) > (float)(G-1) ? G-1 : (int)(me.x * INV_CS);
    const int cy = (me.y * INV_CS) > (float)(G-1) ? G-1 : (int)(me.y * INV_CS);
    const int cz = (me.z * INV_CS) > (float)(G-1) ? G-1 : (int)(me.z * INV_CS);

    const double BIGP = __hiloint2double(__float_as_int(BIGF), -1);
    double m0, m1, m2;
    int R = 1;
    for (;;) {
        m0 = BIGP; m1 = BIGP; m2 = BIGP;
        const int x0 = max(cx - R, 0), x1 = min(cx + R, G-1);
        const int y0 = max(cy - R, 0), y1 = min(cy + R, G-1);
        const int z0 = max(cz - R, 0), z1 = min(cz + R, G-1);
        for (int gx = x0; gx <= x1; ++gx) {
            for (int gy = y0; gy <= y1; ++gy) {
                const int base = (gx << 6) | (gy << 3);
                const int q0 = csl[base + z0];
                const int q1 = csl[base + z1 + 1];
                for (int q = q0 + sub; q < q1; q += SPLIT) {
                    const float4 c = sorted[segbase + q];
                    const float dx = me.x - c.x;
                    const float dy = me.y - c.y;
                    const float dz = me.z - c.z;
                    float d2 = fmaf(dx, dx, fmaf(dy, dy, dz * dz));
                    if (q == j) d2 = BIGF;                // self
                    pk_insert(__hiloint2double(__float_as_int(d2),
                                               __float_as_int(c.w)),
                              m0, m1, m2);
                }
            }
        }
        // butterfly merge across the 8 lanes of this point (partners always
        // share the same R-loop iteration count -> exec-mask safe)
        #pragma unroll
        for (int mask = 1; mask < SPLIT; mask <<= 1) {
            const double o0 = __shfl_xor(m0, mask);
            const double o1 = __shfl_xor(m1, mask);
            const double o2 = __shfl_xor(m2, mask);
            pk_insert(o0, m0, m1, m2);
            pk_insert(o1, m0, m1, m2);
            pk_insert(o2, m0, m1, m2);
        }
        const float d3 = __uint_as_float((unsigned)__double2hiint(m2));
        const float g = (float)R * CS;
        if (d3 <= g * g || R >= G) break;
        ++R;   // exactness guard failed (rare, boundary points) — widen box
    }

    // ---- epilogue: sim/tsim loss for the 3 neighbors (lane sub==0 only) ----
    float loss = 0.0f;
    if (sub == 0) {
        const int nbr[KNN] = { __double2loint(m0), __double2loint(m1), __double2loint(m2) };

        const long gp = segbase + myorig;
        const float px = pred[gp*3+0], py = pred[gp*3+1], pz = pred[gp*3+2];
        const float inp = sqrtf(px*px + py*py + pz*pz + 1e-8f) + 1e-10f;
        const float qx = px / inp, qy = py / inp, qz = pz / inp;
        const float tx = target[gp*3+0], ty = target[gp*3+1], tz = target[gp*3+2];

        #pragma unroll
        for (int k = 0; k < KNN; ++k) {
            const long gn = segbase + nbr[k];
            const float nx = pred[gn*3+0], ny = pred[gn*3+1], nz = pred[gn*3+2];
            const float ninp = sqrtf(nx*nx + ny*ny + nz*nz + 1e-8f) + 1e-10f;
            float sim = fabsf((nx*qx + ny*qy + nz*qz) / ninp);
            sim = fminf(sim, 1.0f);
            const float ux = target[gn*3+0], uy = target[gn*3+1], uz = target[gn*3+2];
            float tsim = fabsf(ux*tx + uy*ty + uz*tz);
            tsim = fminf(tsim, 1.0f);
            const float diff = sim - tsim;
            loss += diff * diff;
        }
    }

    // wave reduce -> LDS -> one atomic per block
    #pragma unroll
    for (int off = 32; off > 0; off >>= 1)
        loss += __shfl_down(loss, off);
    if ((tid & 63) == 0) wred[tid >> 6] = loss;
    __syncthreads();
    if (tid == 0) {
        float ssum = 0.0f;
        #pragma unroll
        for (int w = 0; w < SEARCH_BLOCK / 64; ++w) ssum += wred[w];
        atomicAdd(out, ssum * inv_total);
    }
}

extern "C" void kernel_launch(void* const* d_in, const int* in_sizes, int n_in,
                              void* d_out, int out_size, void* d_ws, size_t ws_size,
                              hipStream_t stream) {
    const float* pred   = (const float*)d_in[0];
    const float* coord  = (const float*)d_in[1];
    const float* target = (const float*)d_in[2];
    float* out = (float*)d_out;

    const int N    = in_sizes[0] / 3;
    const int nseg = in_sizes[3];
    const int seg  = N / nseg;           // 4096

    // workspace layout (16B aligned slabs)
    char* ws = (char*)d_ws;
    float4* sorted   = (float4*)ws;                       ws += (size_t)N * sizeof(float4);
    int* cellstart   = (int*)ws;                          ws += (size_t)nseg * (NCELL + 1) * sizeof(int);
    ws = (char*)(((size_t)ws + 15) & ~(size_t)15);
    int* cursor      = (int*)ws;                          ws += (size_t)nseg * NCELL * sizeof(int);
    int* hist        = (int*)ws;                          ws += (size_t)nseg * NCELL * sizeof(int);
    int* pcell       = (int*)ws;

    hipMemsetAsync(hist, 0, (size_t)nseg * NCELL * sizeof(int), stream);
    hipMemsetAsync(out, 0, sizeof(float), stream);

    const int pblocks = (N + HIST_BLOCK - 1) / HIST_BLOCK;
    hist_kernel<<<pblocks, HIST_BLOCK, 0, stream>>>(coord, pcell, hist, N);
    scan_kernel<<<nseg, SCAN_BLOCK, 0, stream>>>(hist, cellstart, cursor);
    scatter_kernel<<<pblocks, HIST_BLOCK, 0, stream>>>(coord, pcell, cursor, sorted, N, seg);

    const float inv_total = 1.0f / ((float)nseg * (float)seg * (float)KNN);
    knn_loss<<<N / PTS_PER_SBLOCK, SEARCH_BLOCK, 0, stream>>>(
        sorted, cellstart, pred, target, out, seg, inv_total);
}

// Round 5
// 78.739 us; speedup vs baseline: 1.1812x; 1.1812x over previous
//
#include <hip/hip_runtime.h>
#include <math.h>

#define G 8                  // grid cells per dim
#define NCELL (G*G*G)        // 512
#define INV_CS 0.8f          // G / 10.0
#define CS 1.25f             // 10.0 / G
#define KNN 3
#define BIGF 3.402823466e+38f

#define BLOCK 512
#define SPLIT 8                                // lanes cooperating per point
#define PTS_PER_BLOCK (BLOCK / SPLIT)          // 64 points searched per block
#define SEG 4096                               // points per segment (asserted via launch math)
#define PPT (SEG / BLOCK)                      // staging points per thread = 8

__device__ __forceinline__ int cell_of(float x, float y, float z) {
    int cx = (int)(x * INV_CS); cx = cx < 0 ? 0 : (cx > G-1 ? G-1 : cx);
    int cy = (int)(y * INV_CS); cy = cy < 0 ? 0 : (cy > G-1 ? G-1 : cy);
    int cz = (int)(z * INV_CS); cz = cz < 0 ? 0 : (cz > G-1 ? G-1 : cz);
    return (cx << 6) | (cy << 3) | cz;
}

__device__ __forceinline__ void pk_insert(double pk, double& m0, double& m1, double& m2) {
    const double lo0 = fmin(m0, pk);
    const double hi0 = fmax(m0, pk);
    m0 = lo0;
    const double lo1 = fmin(m1, hi0);
    const double hi1 = fmax(m1, hi0);
    m1 = lo1;
    m2 = fmin(m2, hi1);
}

// One kernel: each block redundantly counting-sorts its whole segment into
// LDS (cell order), then does exact 3-NN + loss for its 64 original points.
// Per-block tie-permutation nondeterminism is self-consistent (block uses
// only its own LDS copy); coverage is exact because blocks own ORIGINAL
// point ranges, not sorted slots.
__global__ __launch_bounds__(BLOCK) void fused_knn_loss(
    const float* __restrict__ pred,
    const float* __restrict__ coord,
    const float* __restrict__ target,
    float* __restrict__ out,
    int seg, int bps,            // bps = blocks per segment = seg / PTS_PER_BLOCK
    float inv_total)
{
    __shared__ float2 sxy[SEG];                 // 32 KB
    __shared__ float  sz[SEG];                  // 16 KB
    __shared__ unsigned short sid[SEG];         //  8 KB
    __shared__ int   csl[NCELL + 1];            //  2 KB
    __shared__ int   hist[NCELL];               //  2 KB (then cursor)
    __shared__ int   wsum[BLOCK / 64];
    __shared__ float wred[BLOCK / 64];
    // total ~60.1 KB -> 2 blocks/CU (160 KB pool), 16 waves/CU

    const int tid = threadIdx.x;
    const int s   = blockIdx.x / bps;
    const long segbase = (long)s * seg;

    // ---- phase 1: load my 8 staging points, histogram cells ----
    hist[tid] = 0;
    __syncthreads();

    float px[PPT], py[PPT], pz[PPT];
    int   pc[PPT];
    #pragma unroll
    for (int k = 0; k < PPT; ++k) {
        const int p = tid + k * BLOCK;
        px[k] = coord[(segbase + p)*3 + 0];
        py[k] = coord[(segbase + p)*3 + 1];
        pz[k] = coord[(segbase + p)*3 + 2];
        pc[k] = cell_of(px[k], py[k], pz[k]);
        atomicAdd(&hist[pc[k]], 1);
    }
    __syncthreads();

    // ---- phase 2: exclusive scan of 512 cell counts (wave-shuffle) ----
    const int own = hist[tid];
    int v = own;
    #pragma unroll
    for (int off = 1; off < 64; off <<= 1) {
        const int t = __shfl_up(v, off);
        if ((tid & 63) >= off) v += t;
    }
    if ((tid & 63) == 63) wsum[tid >> 6] = v;
    __syncthreads();
    if (tid < 64) {                              // wave 0 scans the 8 wave sums
        int w = (tid < 8) ? wsum[tid] : 0;
        #pragma unroll
        for (int off = 1; off < 8; off <<= 1) {
            const int t = __shfl_up(w, off);
            if (tid >= off) w += t;
        }
        if (tid < 8) wsum[tid] = w;
    }
    __syncthreads();
    const int wid  = tid >> 6;
    const int incl = v + (wid ? wsum[wid - 1] : 0);
    const int excl = incl - own;
    csl[tid] = excl;
    if (tid == BLOCK - 1) csl[NCELL] = incl;     // == seg
    hist[tid] = excl;                            // becomes scatter cursor
    __syncthreads();

    // ---- phase 3: scatter into cell-sorted LDS ----
    #pragma unroll
    for (int k = 0; k < PPT; ++k) {
        const int slot = atomicAdd(&hist[pc[k]], 1);
        sxy[slot] = make_float2(px[k], py[k]);
        sz[slot]  = pz[k];
        sid[slot] = (unsigned short)(tid + k * BLOCK);
    }
    __syncthreads();

    // ---- phase 4: exact 3-NN for my 64 ORIGINAL points (8 lanes/point) ----
    const int sub   = tid & (SPLIT - 1);
    const int grp   = tid >> 3;
    const int jloc  = (blockIdx.x % bps) * PTS_PER_BLOCK + grp;  // original local idx
    const float mx = coord[(segbase + jloc)*3 + 0];              // 8-lane broadcast
    const float my = coord[(segbase + jloc)*3 + 1];
    const float mz = coord[(segbase + jloc)*3 + 2];
    const int cx = (mx * INV_CS) > (float)(G-1) ? G-1 : (int)(mx * INV_CS);
    const int cy = (my * INV_CS) > (float)(G-1) ? G-1 : (int)(my * INV_CS);
    const int cz = (mz * INV_CS) > (float)(G-1) ? G-1 : (int)(mz * INV_CS);

    const double BIGP = __hiloint2double(__float_as_int(BIGF), -1);
    double m0, m1, m2;
    int R = 1;
    for (;;) {
        m0 = BIGP; m1 = BIGP; m2 = BIGP;
        const int x0 = max(cx - R, 0), x1 = min(cx + R, G-1);
        const int y0 = max(cy - R, 0), y1 = min(cy + R, G-1);
        const int z0 = max(cz - R, 0), z1 = min(cz + R, G-1);
        for (int gx = x0; gx <= x1; ++gx) {
            for (int gy = y0; gy <= y1; ++gy) {
                const int base = (gx << 6) | (gy << 3);
                const int q0 = csl[base + z0];
                const int q1 = csl[base + z1 + 1];
                for (int q = q0 + sub; q < q1; q += SPLIT) {
                    const float2 xy = sxy[q];
                    const float  zz = sz[q];
                    const int    id = sid[q];
                    const float dx = mx - xy.x;
                    const float dy = my - xy.y;
                    const float dz = mz - zz;
                    float d2 = fmaf(dx, dx, fmaf(dy, dy, dz * dz));
                    if (id == jloc) d2 = BIGF;                 // exclude self
                    pk_insert(__hiloint2double(__float_as_int(d2), id),
                              m0, m1, m2);
                }
            }
        }
        // butterfly merge across the 8 lanes of this point
        #pragma unroll
        for (int mask = 1; mask < SPLIT; mask <<= 1) {
            const double o0 = __shfl_xor(m0, mask);
            const double o1 = __shfl_xor(m1, mask);
            const double o2 = __shfl_xor(m2, mask);
            pk_insert(o0, m0, m1, m2);
            pk_insert(o1, m0, m1, m2);
            pk_insert(o2, m0, m1, m2);
        }
        const float d3 = __uint_as_float((unsigned)__double2hiint(m2));
        const float g = (float)R * CS;
        if (d3 <= g * g || R >= G) break;
        ++R;   // exactness guard failed (rare boundary case) — widen box
    }

    // ---- epilogue: sim/tsim loss (lane sub==0 of each group) ----
    float loss = 0.0f;
    if (sub == 0) {
        const int nbr[KNN] = { __double2loint(m0), __double2loint(m1), __double2loint(m2) };
        const long gp = segbase + jloc;
        const float ppx = pred[gp*3+0], ppy = pred[gp*3+1], ppz = pred[gp*3+2];
        const float inp = sqrtf(ppx*ppx + ppy*ppy + ppz*ppz + 1e-8f) + 1e-10f;
        const float qx = ppx / inp, qy = ppy / inp, qz = ppz / inp;
        const float tx = target[gp*3+0], ty = target[gp*3+1], tz = target[gp*3+2];

        #pragma unroll
        for (int k = 0; k < KNN; ++k) {
            const long gn = segbase + nbr[k];
            const float nx = pred[gn*3+0], ny = pred[gn*3+1], nz = pred[gn*3+2];
            const float ninp = sqrtf(nx*nx + ny*ny + nz*nz + 1e-8f) + 1e-10f;
            float sim = fabsf((nx*qx + ny*qy + nz*qz) / ninp);
            sim = fminf(sim, 1.0f);
            const float ux = target[gn*3+0], uy = target[gn*3+1], uz = target[gn*3+2];
            float tsim = fabsf(ux*tx + uy*ty + uz*tz);
            tsim = fminf(tsim, 1.0f);
            const float diff = sim - tsim;
            loss += diff * diff;
        }
    }

    // wave reduce -> LDS -> one atomic per block
    #pragma unroll
    for (int off = 32; off > 0; off >>= 1)
        loss += __shfl_down(loss, off);
    if ((tid & 63) == 0) wred[tid >> 6] = loss;
    __syncthreads();
    if (tid == 0) {
        float ssum = 0.0f;
        #pragma unroll
        for (int w = 0; w < BLOCK / 64; ++w) ssum += wred[w];
        atomicAdd(out, ssum * inv_total);
    }
}

extern "C" void kernel_launch(void* const* d_in, const int* in_sizes, int n_in,
                              void* d_out, int out_size, void* d_ws, size_t ws_size,
                              hipStream_t stream) {
    const float* pred   = (const float*)d_in[0];
    const float* coord  = (const float*)d_in[1];
    const float* target = (const float*)d_in[2];
    float* out = (float*)d_out;

    const int N    = in_sizes[0] / 3;
    const int nseg = in_sizes[3];
    const int seg  = N / nseg;                  // 4096
    const int bps  = seg / PTS_PER_BLOCK;       // 64

    hipMemsetAsync(out, 0, sizeof(float), stream);

    const float inv_total = 1.0f / ((float)nseg * (float)seg * (float)KNN);
    fused_knn_loss<<<N / PTS_PER_BLOCK, BLOCK, 0, stream>>>(
        pred, coord, target, out, seg, bps, inv_total);
}

// Round 6
// 76.290 us; speedup vs baseline: 1.2191x; 1.0321x over previous
//
#include <hip/hip_runtime.h>
#include <math.h>

#define G 8                  // grid cells per dim
#define NCELL (G*G*G)        // 512
#define INV_CS 0.8f          // G / 10.0
#define CS 1.25f             // 10.0 / G
#define KNN 3
#define BIGF 3.402823466e+38f

#define BLOCK 1024
#define SPLIT 8                                // lanes cooperating per point
#define PTS_PER_BLOCK (BLOCK / SPLIT)          // 128 points searched per block
#define SEG 4096                               // points per segment
#define PPT (SEG / BLOCK)                      // staging points per thread = 4

__device__ __forceinline__ int cell_of(float x, float y, float z) {
    int cx = (int)(x * INV_CS); cx = cx < 0 ? 0 : (cx > G-1 ? G-1 : cx);
    int cy = (int)(y * INV_CS); cy = cy < 0 ? 0 : (cy > G-1 ? G-1 : cy);
    int cz = (int)(z * INV_CS); cz = cz < 0 ? 0 : (cz > G-1 ? G-1 : cz);
    return (cx << 6) | (cy << 3) | cz;
}

__device__ __forceinline__ void pk_insert(double pk, double& m0, double& m1, double& m2) {
    const double lo0 = fmin(m0, pk);
    const double hi0 = fmax(m0, pk);
    m0 = lo0;
    const double lo1 = fmin(m1, hi0);
    const double hi1 = fmax(m1, hi0);
    m1 = lo1;
    m2 = fmin(m2, hi1);
}

// One kernel: each block redundantly counting-sorts its whole segment into
// LDS (cell order), then does exact 3-NN + loss for its 128 original points.
// 256 blocks x 1024 threads: one block (16 waves) per CU -> each CU performs
// ONE segment sort (vs two in the 512x512 layout) at identical occupancy.
__global__ __launch_bounds__(BLOCK) void fused_knn_loss(
    const float* __restrict__ pred,
    const float* __restrict__ coord,
    const float* __restrict__ target,
    float* __restrict__ out,
    int seg, int bps,            // bps = blocks per segment = seg / PTS_PER_BLOCK
    float inv_total)
{
    __shared__ float2 sxy[SEG];                 // 32 KB
    __shared__ float  sz[SEG];                  // 16 KB
    __shared__ unsigned short sid[SEG];         //  8 KB
    __shared__ int   csl[NCELL + 1];            //  2 KB
    __shared__ int   hist[NCELL];               //  2 KB (then cursor)
    __shared__ int   wsum[BLOCK / 64];
    __shared__ float wred[BLOCK / 64];
    // total ~61.5 KB

    const int tid = threadIdx.x;
    const int s   = blockIdx.x / bps;
    const long segbase = (long)s * seg;

    // ---- phase 1: load my 4 staging points, histogram cells ----
    if (tid < NCELL) hist[tid] = 0;
    __syncthreads();

    float px[PPT], py[PPT], pz[PPT];
    int   pc[PPT];
    #pragma unroll
    for (int k = 0; k < PPT; ++k) {
        const int p = tid + k * BLOCK;
        px[k] = coord[(segbase + p)*3 + 0];
        py[k] = coord[(segbase + p)*3 + 1];
        pz[k] = coord[(segbase + p)*3 + 2];
        pc[k] = cell_of(px[k], py[k], pz[k]);
        atomicAdd(&hist[pc[k]], 1);
    }
    __syncthreads();

    // ---- phase 2: exclusive scan of 512 cell counts (wave-shuffle) ----
    int own = 0;
    if (tid < NCELL) own = hist[tid];
    int v = own;
    #pragma unroll
    for (int off = 1; off < 64; off <<= 1) {
        const int t = __shfl_up(v, off);
        if ((tid & 63) >= off) v += t;
    }
    if (tid < NCELL && (tid & 63) == 63) wsum[tid >> 6] = v;
    __syncthreads();
    if (tid < 64) {                              // wave 0 scans the 8 wave sums
        int w = (tid < NCELL / 64) ? wsum[tid] : 0;
        #pragma unroll
        for (int off = 1; off < NCELL / 64; off <<= 1) {
            const int t = __shfl_up(w, off);
            if (tid >= off) w += t;
        }
        if (tid < NCELL / 64) wsum[tid] = w;
    }
    __syncthreads();
    if (tid < NCELL) {
        const int wid  = tid >> 6;
        const int incl = v + (wid ? wsum[wid - 1] : 0);
        const int excl = incl - own;
        csl[tid] = excl;
        if (tid == NCELL - 1) csl[NCELL] = incl; // == seg
        hist[tid] = excl;                        // becomes scatter cursor
    }
    __syncthreads();

    // ---- phase 3: scatter into cell-sorted LDS ----
    #pragma unroll
    for (int k = 0; k < PPT; ++k) {
        const int slot = atomicAdd(&hist[pc[k]], 1);
        sxy[slot] = make_float2(px[k], py[k]);
        sz[slot]  = pz[k];
        sid[slot] = (unsigned short)(tid + k * BLOCK);
    }
    __syncthreads();

    // ---- phase 4: exact 3-NN for my 128 ORIGINAL points (8 lanes/point) ----
    const int sub   = tid & (SPLIT - 1);
    const int grp   = tid >> 3;
    const int jloc  = (blockIdx.x % bps) * PTS_PER_BLOCK + grp;  // original local idx
    const float mx = coord[(segbase + jloc)*3 + 0];              // 8-lane broadcast
    const float my = coord[(segbase + jloc)*3 + 1];
    const float mz = coord[(segbase + jloc)*3 + 2];
    const int cx = (mx * INV_CS) > (float)(G-1) ? G-1 : (int)(mx * INV_CS);
    const int cy = (my * INV_CS) > (float)(G-1) ? G-1 : (int)(my * INV_CS);
    const int cz = (mz * INV_CS) > (float)(G-1) ? G-1 : (int)(mz * INV_CS);

    const double BIGP = __hiloint2double(__float_as_int(BIGF), -1);
    double m0, m1, m2;
    int R = 1;
    for (;;) {
        m0 = BIGP; m1 = BIGP; m2 = BIGP;
        const int x0 = max(cx - R, 0), x1 = min(cx + R, G-1);
        const int y0 = max(cy - R, 0), y1 = min(cy + R, G-1);
        const int z0 = max(cz - R, 0), z1 = min(cz + R, G-1);
        for (int gx = x0; gx <= x1; ++gx) {
            for (int gy = y0; gy <= y1; ++gy) {
                const int base = (gx << 6) | (gy << 3);
                const int q0 = csl[base + z0];
                const int q1 = csl[base + z1 + 1];
                for (int q = q0 + sub; q < q1; q += SPLIT) {
                    const float2 xy = sxy[q];
                    const float  zz = sz[q];
                    const int    id = sid[q];
                    const float dx = mx - xy.x;
                    const float dy = my - xy.y;
                    const float dz = mz - zz;
                    float d2 = fmaf(dx, dx, fmaf(dy, dy, dz * dz));
                    if (id == jloc) d2 = BIGF;                 // exclude self
                    pk_insert(__hiloint2double(__float_as_int(d2), id),
                              m0, m1, m2);
                }
            }
        }
        // butterfly merge across the 8 lanes of this point
        #pragma unroll
        for (int mask = 1; mask < SPLIT; mask <<= 1) {
            const double o0 = __shfl_xor(m0, mask);
            const double o1 = __shfl_xor(m1, mask);
            const double o2 = __shfl_xor(m2, mask);
            pk_insert(o0, m0, m1, m2);
            pk_insert(o1, m0, m1, m2);
            pk_insert(o2, m0, m1, m2);
        }
        const float d3 = __uint_as_float((unsigned)__double2hiint(m2));
        const float g = (float)R * CS;
        if (d3 <= g * g || R >= G) break;
        ++R;   // exactness guard failed (rare boundary case) — widen box
    }

    // ---- epilogue: sim/tsim loss (lane sub==0 of each group) ----
    float loss = 0.0f;
    if (sub == 0) {
        const int nbr[KNN] = { __double2loint(m0), __double2loint(m1), __double2loint(m2) };
        const long gp = segbase + jloc;
        const float ppx = pred[gp*3+0], ppy = pred[gp*3+1], ppz = pred[gp*3+2];
        const float inp = sqrtf(ppx*ppx + ppy*ppy + ppz*ppz + 1e-8f) + 1e-10f;
        const float qx = ppx / inp, qy = ppy / inp, qz = ppz / inp;
        const float tx = target[gp*3+0], ty = target[gp*3+1], tz = target[gp*3+2];

        #pragma unroll
        for (int k = 0; k < KNN; ++k) {
            const long gn = segbase + nbr[k];
            const float nx = pred[gn*3+0], ny = pred[gn*3+1], nz = pred[gn*3+2];
            const float ninp = sqrtf(nx*nx + ny*ny + nz*nz + 1e-8f) + 1e-10f;
            float sim = fabsf((nx*qx + ny*qy + nz*qz) / ninp);
            sim = fminf(sim, 1.0f);
            const float ux = target[gn*3+0], uy = target[gn*3+1], uz = target[gn*3+2];
            float tsim = fabsf(ux*tx + uy*ty + uz*tz);
            tsim = fminf(tsim, 1.0f);
            const float diff = sim - tsim;
            loss += diff * diff;
        }
    }

    // wave reduce -> LDS -> one atomic per block
    #pragma unroll
    for (int off = 32; off > 0; off >>= 1)
        loss += __shfl_down(loss, off);
    if ((tid & 63) == 0) wred[tid >> 6] = loss;
    __syncthreads();
    if (tid == 0) {
        float ssum = 0.0f;
        #pragma unroll
        for (int w = 0; w < BLOCK / 64; ++w) ssum += wred[w];
        atomicAdd(out, ssum * inv_total);
    }
}

extern "C" void kernel_launch(void* const* d_in, const int* in_sizes, int n_in,
                              void* d_out, int out_size, void* d_ws, size_t ws_size,
                              hipStream_t stream) {
    const float* pred   = (const float*)d_in[0];
    const float* coord  = (const float*)d_in[1];
    const float* target = (const float*)d_in[2];
    float* out = (float*)d_out;

    const int N    = in_sizes[0] / 3;
    const int nseg = in_sizes[3];
    const int seg  = N / nseg;                  // 4096
    const int bps  = seg / PTS_PER_BLOCK;       // 32

    hipMemsetAsync(out, 0, sizeof(float), stream);

    const float inv_total = 1.0f / ((float)nseg * (float)seg * (float)KNN);
    fused_knn_loss<<<N / PTS_PER_BLOCK, BLOCK, 0, stream>>>(
        pred, coord, target, out, seg, bps, inv_total);
}

// Round 7
// 73.725 us; speedup vs baseline: 1.2615x; 1.0348x over previous
//
#include <hip/hip_runtime.h>
#include <math.h>

#define G 8                  // grid cells per dim
#define NCELL (G*G*G)        // 512
#define INV_CS 0.8f          // G / 10.0
#define CS 1.25f             // 10.0 / G
#define KNN 3
#define BIGF 3.402823466e+38f

#define BLOCK 1024
#define SPLIT 8                                // lanes cooperating per point
#define PTS_PER_BLOCK (BLOCK / SPLIT)          // 128 points searched per block
#define SEG 4096                               // points per segment
#define PPT (SEG / BLOCK)                      // staging points per thread = 4

#define KEYMASK 0xFFFFF000u                    // 20-bit d2 | 12-bit id
#define BIGK    0xFFFFFFFFu

__device__ __forceinline__ int cell_of(float x, float y, float z) {
    int cx = (int)(x * INV_CS); cx = cx < 0 ? 0 : (cx > G-1 ? G-1 : cx);
    int cy = (int)(y * INV_CS); cy = cy < 0 ? 0 : (cy > G-1 ? G-1 : cy);
    int cz = (int)(z * INV_CS); cz = cz < 0 ? 0 : (cz > G-1 ? G-1 : cz);
    return (cx << 6) | (cy << 3) | cz;
}

// branchless top-3 (ascending) on u32 keys: 5 min/max
__device__ __forceinline__ void pk_insert(unsigned k, unsigned& m0, unsigned& m1, unsigned& m2) {
    const unsigned lo0 = min(m0, k);
    const unsigned hi0 = max(m0, k);
    m0 = lo0;
    const unsigned lo1 = min(m1, hi0);
    const unsigned hi1 = max(m1, hi0);
    m1 = lo1;
    m2 = min(m2, hi1);
}

// One kernel: each block redundantly counting-sorts its whole segment into
// LDS (cell order), then does exact 3-NN + loss for its 128 original points.
// Key = (d2_bits & 0xFFFFF000) | id : d2 >= 0 (sum of squares, no
// cancellation) so positive-float bit patterns order as u32; key is
// independent of scatter order -> deterministic result.
__global__ __launch_bounds__(BLOCK) void fused_knn_loss(
    const float* __restrict__ pred,
    const float* __restrict__ coord,
    const float* __restrict__ target,
    float* __restrict__ out,
    int seg, int bps,            // bps = blocks per segment = seg / PTS_PER_BLOCK
    float inv_total)
{
    __shared__ float2 sxy[SEG];                 // 32 KB
    __shared__ float  sz[SEG];                  // 16 KB
    __shared__ unsigned short sid[SEG];         //  8 KB
    __shared__ int   csl[NCELL + 1];            //  2 KB
    __shared__ int   hist[NCELL];               //  2 KB (then cursor)
    __shared__ int   wsum[BLOCK / 64];
    __shared__ float wred[BLOCK / 64];
    // total ~61.5 KB

    const int tid = threadIdx.x;
    const int s   = blockIdx.x / bps;
    const long segbase = (long)s * seg;

    // ---- phase 1: load my 4 staging points, histogram cells ----
    if (tid < NCELL) hist[tid] = 0;
    __syncthreads();

    float px[PPT], py[PPT], pz[PPT];
    int   pc[PPT];
    #pragma unroll
    for (int k = 0; k < PPT; ++k) {
        const int p = tid + k * BLOCK;
        px[k] = coord[(segbase + p)*3 + 0];
        py[k] = coord[(segbase + p)*3 + 1];
        pz[k] = coord[(segbase + p)*3 + 2];
        pc[k] = cell_of(px[k], py[k], pz[k]);
        atomicAdd(&hist[pc[k]], 1);
    }
    __syncthreads();

    // ---- phase 2: exclusive scan of 512 cell counts (wave-shuffle) ----
    int own = 0;
    if (tid < NCELL) own = hist[tid];
    int v = own;
    #pragma unroll
    for (int off = 1; off < 64; off <<= 1) {
        const int t = __shfl_up(v, off);
        if ((tid & 63) >= off) v += t;
    }
    if (tid < NCELL && (tid & 63) == 63) wsum[tid >> 6] = v;
    __syncthreads();
    if (tid < 64) {                              // wave 0 scans the 8 wave sums
        int w = (tid < NCELL / 64) ? wsum[tid] : 0;
        #pragma unroll
        for (int off = 1; off < NCELL / 64; off <<= 1) {
            const int t = __shfl_up(w, off);
            if (tid >= off) w += t;
        }
        if (tid < NCELL / 64) wsum[tid] = w;
    }
    __syncthreads();
    if (tid < NCELL) {
        const int wid  = tid >> 6;
        const int incl = v + (wid ? wsum[wid - 1] : 0);
        const int excl = incl - own;
        csl[tid] = excl;
        if (tid == NCELL - 1) csl[NCELL] = incl; // == seg
        hist[tid] = excl;                        // becomes scatter cursor
    }
    __syncthreads();

    // ---- phase 3: scatter into cell-sorted LDS ----
    #pragma unroll
    for (int k = 0; k < PPT; ++k) {
        const int slot = atomicAdd(&hist[pc[k]], 1);
        sxy[slot] = make_float2(px[k], py[k]);
        sz[slot]  = pz[k];
        sid[slot] = (unsigned short)(tid + k * BLOCK);
    }
    __syncthreads();

    // ---- phase 4: exact 3-NN for my 128 ORIGINAL points (8 lanes/point) ----
    const int sub   = tid & (SPLIT - 1);
    const int grp   = tid >> 3;
    const int jloc  = (blockIdx.x % bps) * PTS_PER_BLOCK + grp;  // original local idx
    const float mx = coord[(segbase + jloc)*3 + 0];              // 8-lane broadcast
    const float my = coord[(segbase + jloc)*3 + 1];
    const float mz = coord[(segbase + jloc)*3 + 2];
    const int cx = (mx * INV_CS) > (float)(G-1) ? G-1 : (int)(mx * INV_CS);
    const int cy = (my * INV_CS) > (float)(G-1) ? G-1 : (int)(my * INV_CS);
    const int cz = (mz * INV_CS) > (float)(G-1) ? G-1 : (int)(mz * INV_CS);

    unsigned m0, m1, m2;
    int R = 1;
    for (;;) {
        m0 = BIGK; m1 = BIGK; m2 = BIGK;
        const int x0 = max(cx - R, 0), x1 = min(cx + R, G-1);
        const int y0 = max(cy - R, 0), y1 = min(cy + R, G-1);
        const int z0 = max(cz - R, 0), z1 = min(cz + R, G-1);
        for (int gx = x0; gx <= x1; ++gx) {
            for (int gy = y0; gy <= y1; ++gy) {
                const int base = (gx << 6) | (gy << 3);
                const int q0 = csl[base + z0];
                const int q1 = csl[base + z1 + 1];
                for (int q = q0 + sub; q < q1; q += SPLIT) {
                    const float2 xy = sxy[q];
                    const float  zz = sz[q];
                    const unsigned id = sid[q];
                    const float dx = mx - xy.x;
                    const float dy = my - xy.y;
                    const float dz = mz - zz;
                    const float d2 = fmaf(dx, dx, fmaf(dy, dy, dz * dz));
                    unsigned key = (__float_as_uint(d2) & KEYMASK) | id;
                    if ((int)id == jloc) key = BIGK;           // exclude self
                    pk_insert(key, m0, m1, m2);
                }
            }
        }
        // butterfly merge across the 8 lanes of this point
        #pragma unroll
        for (int mask = 1; mask < SPLIT; mask <<= 1) {
            const unsigned o0 = __shfl_xor(m0, mask);
            const unsigned o1 = __shfl_xor(m1, mask);
            const unsigned o2 = __shfl_xor(m2, mask);
            pk_insert(o0, m0, m1, m2);
            pk_insert(o1, m0, m1, m2);
            pk_insert(o2, m0, m1, m2);
        }
        // guard: truncated d3 underestimates true d3 by <= 2^-11 rel; use
        // 0.999 safety factor so the box-coverage proof still holds.
        const float d3 = __uint_as_float(m2 & KEYMASK);
        const float g = (float)R * CS;
        if (d3 <= g * g * 0.999f || R >= G) break;
        ++R;   // exactness guard failed (rare boundary case) — widen box
    }

    // ---- epilogue: lanes sub=0,1,2 each handle one neighbor ----
    float loss = 0.0f;
    if (sub < KNN) {
        const unsigned mk = (sub == 0) ? m0 : (sub == 1) ? m1 : m2;
        const int nk = (int)(mk & 0xFFFu);
        const long gp = segbase + jloc;
        const float ppx = pred[gp*3+0], ppy = pred[gp*3+1], ppz = pred[gp*3+2];
        const float inp = sqrtf(ppx*ppx + ppy*ppy + ppz*ppz + 1e-8f) + 1e-10f;
        const float qx = ppx / inp, qy = ppy / inp, qz = ppz / inp;
        const float tx = target[gp*3+0], ty = target[gp*3+1], tz = target[gp*3+2];

        const long gn = segbase + nk;
        const float nx = pred[gn*3+0], ny = pred[gn*3+1], nz = pred[gn*3+2];
        const float ninp = sqrtf(nx*nx + ny*ny + nz*nz + 1e-8f) + 1e-10f;
        float sim = fabsf((nx*qx + ny*qy + nz*qz) / ninp);
        sim = fminf(sim, 1.0f);
        const float ux = target[gn*3+0], uy = target[gn*3+1], uz = target[gn*3+2];
        float tsim = fabsf(ux*tx + uy*ty + uz*tz);
        tsim = fminf(tsim, 1.0f);
        const float diff = sim - tsim;
        loss = diff * diff;
    }

    // wave reduce -> LDS -> one atomic per block
    #pragma unroll
    for (int off = 32; off > 0; off >>= 1)
        loss += __shfl_down(loss, off);
    if ((tid & 63) == 0) wred[tid >> 6] = loss;
    __syncthreads();
    if (tid == 0) {
        float ssum = 0.0f;
        #pragma unroll
        for (int w = 0; w < BLOCK / 64; ++w) ssum += wred[w];
        atomicAdd(out, ssum * inv_total);
    }
}

extern "C" void kernel_launch(void* const* d_in, const int* in_sizes, int n_in,
                              void* d_out, int out_size, void* d_ws, size_t ws_size,
                              hipStream_t stream) {
    const float* pred   = (const float*)d_in[0];
    const float* coord  = (const float*)d_in[1];
    const float* target = (const float*)d_in[2];
    float* out = (float*)d_out;

    const int N    = in_sizes[0] / 3;
    const int nseg = in_sizes[3];
    const int seg  = N / nseg;                  // 4096
    const int bps  = seg / PTS_PER_BLOCK;       // 32

    hipMemsetAsync(out, 0, sizeof(float), stream);

    const float inv_total = 1.0f / ((float)nseg * (float)seg * (float)KNN);
    fused_knn_loss<<<N / PTS_PER_BLOCK, BLOCK, 0, stream>>>(
        pred, coord, target, out, seg, bps, inv_total);
}